// Round 8
// baseline (1327.952 us; speedup 1.0000x reference)
//
#include <hip/hip_runtime.h>

// AffinityPropagate (CSPN): B=8, C=32, H=W=256, K=3, prop_time=16.
// R7: CPB 2->1 (LDS 36->18 KB) to lift occupancy 16->32 waves/CU;
// __launch_bounds__(256,8) pins VGPR<=64 (8 waves/SIMD cliff).
// Pixel-major weights + shfl halos kept from R4 (bank conflicts = 0).

#define B_ 8
#define C_ 32
#define H_ 256
#define W_ 256
#define STRIP 16
#define MIDR (STRIP + 2)

// Pixel-major weights: wts[((b*H+h)*W+w)*9 + j]
__global__ __launch_bounds__(256)
void prep_weights_kernel(const float* __restrict__ guided,
                         const float* __restrict__ depth,
                         float* __restrict__ wts,
                         int total /* B*H*W */) {
    int idx = blockIdx.x * 256 + threadIdx.x;
    if (idx >= total) return;
    int b  = idx >> 16;        // H*W = 65536
    int hw = idx & 0xFFFF;
    const float* gp = guided + (((size_t)b * 8) << 16) + hw;
    float g[8];
    float m = -3.4e38f;
#pragma unroll
    for (int j = 0; j < 8; j++) { g[j] = gp[(size_t)j << 16]; m = fmaxf(m, g[j]); }
    float s = 0.f;
#pragma unroll
    for (int j = 0; j < 8; j++) { g[j] = expf(g[j] - m); s += g[j]; }
    float inv = 1.0f / s;
    float d = depth[(((size_t)b) << 16) + hw];
    bool fixed = d > 0.f;   // sign(depth) is 0/1 (depth >= 0)
    float* wp = wts + (size_t)idx * 9;
#pragma unroll
    for (int j = 0; j < 9; j++) {
        float v;
        if (j == 4) v = fixed ? 1.f : 0.f;            // center
        else        v = fixed ? 0.f : g[j - (j > 4 ? 1 : 0)] * inv;
        wp[j] = v;
    }
}

// acc[k] += wf[9k + (3i+j)] * rb[i][k+j]  — same fmaf order as R3/R4 (passed).
__device__ __forceinline__ void stencil4(const float wf[36],
                                         const float rb[3][6],
                                         float acc[4]) {
#pragma unroll
    for (int i = 0; i < 3; ++i)
#pragma unroll
        for (int j = 0; j < 3; ++j)
#pragma unroll
            for (int k = 0; k < 4; ++k)
                acc[k] = fmaf(wf[9 * k + i * 3 + j], rb[i][k + j], acc[k]);
}

// Two fused propagation steps, one channel per block. Block (64,4): one wave
// == one full 256-wide row. Halos via wave shfl (no scalar loads).
__global__ __launch_bounds__(256, 8)
void prop2_kernel(const float* __restrict__ xin,
                  const float* __restrict__ wts,
                  float* __restrict__ xout) {
    __shared__ float mid[MIDR][W_];        // 18 KB
    const int tx = threadIdx.x;            // 0..63
    const int ty = threadIdx.y;            // 0..3
    const int h0 = blockIdx.x * STRIP;
    const int c  = blockIdx.y;
    const int b  = blockIdx.z;
    const int w0 = tx * 4;
    const size_t plane = (size_t)H_ * W_;
    const bool hasL = (tx > 0), hasR = (tx < 63);
    const float* xc = xin + ((size_t)b * C_ + c) * plane;

    // ---- Phase 1: step-1 on rows h0-1 .. h0+STRIP, into LDS ----
    for (int rr = ty; rr < MIDR; rr += 4) {
        const int r = h0 - 1 + rr;
        if (r < 0 || r >= H_) {
            float4 z = {0.f, 0.f, 0.f, 0.f};
            *reinterpret_cast<float4*>(&mid[rr][w0]) = z;
            continue;
        }
        const float* wp = wts + ((size_t)(b * H_ + r) * W_ + w0) * 9;
        float wf[36];
#pragma unroll
        for (int j = 0; j < 9; ++j)
            *reinterpret_cast<float4*>(&wf[4 * j]) =
                *reinterpret_cast<const float4*>(wp + 4 * j);
        float rb[3][6];
#pragma unroll
        for (int i = 0; i < 3; ++i) {
            int row = r - 1 + i;
            if (row >= 0 && row < H_) {
                float4 v = *reinterpret_cast<const float4*>(
                    xc + (size_t)row * W_ + w0);
                float lh = __shfl_up(v.w, 1);
                float rhv = __shfl_down(v.x, 1);
                rb[i][0] = hasL ? lh : 0.f;
                rb[i][1] = v.x; rb[i][2] = v.y; rb[i][3] = v.z; rb[i][4] = v.w;
                rb[i][5] = hasR ? rhv : 0.f;
            } else {
#pragma unroll
                for (int t = 0; t < 6; ++t) rb[i][t] = 0.f;
            }
        }
        float acc[4] = {0.f, 0.f, 0.f, 0.f};
        stencil4(wf, rb, acc);
        float4 o = {acc[0], acc[1], acc[2], acc[3]};
        *reinterpret_cast<float4*>(&mid[rr][w0]) = o;
    }
    __syncthreads();

    // ---- Phase 2: step-2 on rows h0 .. h0+STRIP-1, LDS -> global ----
    for (int rr = ty; rr < STRIP; rr += 4) {
        const int r = h0 + rr;
        const float* wp = wts + ((size_t)(b * H_ + r) * W_ + w0) * 9;
        float wf[36];
#pragma unroll
        for (int j = 0; j < 9; ++j)
            *reinterpret_cast<float4*>(&wf[4 * j]) =
                *reinterpret_cast<const float4*>(wp + 4 * j);
        float rb[3][6];
#pragma unroll
        for (int i = 0; i < 3; ++i) {
            // mid index rr+i corresponds to global row r-1+i
            float4 v = *reinterpret_cast<const float4*>(&mid[rr + i][w0]);
            float lh = __shfl_up(v.w, 1);
            float rhv = __shfl_down(v.x, 1);
            rb[i][0] = hasL ? lh : 0.f;
            rb[i][1] = v.x; rb[i][2] = v.y; rb[i][3] = v.z; rb[i][4] = v.w;
            rb[i][5] = hasR ? rhv : 0.f;
        }
        float acc[4] = {0.f, 0.f, 0.f, 0.f};
        stencil4(wf, rb, acc);
        float4 o = {acc[0], acc[1], acc[2], acc[3]};
        *reinterpret_cast<float4*>(xout + ((size_t)b * C_ + c) * plane +
                                   (size_t)r * W_ + w0) = o;
    }
}

extern "C" void kernel_launch(void* const* d_in, const int* in_sizes, int n_in,
                              void* d_out, int out_size, void* d_ws, size_t ws_size,
                              hipStream_t stream) {
    const float* x      = (const float*)d_in[0];
    const float* guided = (const float*)d_in[1];
    const float* depth  = (const float*)d_in[2];
    // d_in[3] = prop_time; fixed to 16 by setup_inputs.
    const int FUSED_STEPS = 8;   // 16 propagation steps, 2 per kernel

    float* xbuf = (float*)d_ws;                                   // 64 MB
    float* wts  = (float*)((char*)d_ws +
                           (size_t)B_ * C_ * H_ * W_ * sizeof(float)); // 18.9 MB
    float* out  = (float*)d_out;

    int total = B_ * H_ * W_;
    hipLaunchKernelGGL(prep_weights_kernel, dim3((total + 255) / 256), dim3(256),
                       0, stream, guided, depth, wts, total);

    dim3 grid(H_ / STRIP, C_, B_), block(64, 4, 1);
    const float* src = x;
    for (int t = 0; t < FUSED_STEPS; ++t) {
        float* dst = (t == FUSED_STEPS - 1) ? out : ((t % 2 == 0) ? xbuf : out);
        hipLaunchKernelGGL(prop2_kernel, grid, block, 0, stream,
                           src, wts, dst);
        src = dst;
    }
}

// Round 9
// 527.836 us; speedup vs baseline: 2.5158x; 2.5158x over previous
//
#include <hip/hip_runtime.h>

// AffinityPropagate (CSPN): B=8, C=32, H=W=256, K=3, prop_time=16.
// R8: revert R7's spill (no min-waves bound; VGPR floats to ~56).
// Occupancy via LDS instead: CPB=2 kept, STRIP 16->8 => mid = 20.5 KB
// => 7 blocks/CU => 28 waves/CU (was 16). Pixel-major weights + shfl halos.

#define B_ 8
#define C_ 32
#define H_ 256
#define W_ 256
#define STRIP 8
#define CPB 2
#define MIDR (STRIP + 2)

// Pixel-major weights: wts[((b*H+h)*W+w)*9 + j]
__global__ __launch_bounds__(256)
void prep_weights_kernel(const float* __restrict__ guided,
                         const float* __restrict__ depth,
                         float* __restrict__ wts,
                         int total /* B*H*W */) {
    int idx = blockIdx.x * 256 + threadIdx.x;
    if (idx >= total) return;
    int b  = idx >> 16;        // H*W = 65536
    int hw = idx & 0xFFFF;
    const float* gp = guided + (((size_t)b * 8) << 16) + hw;
    float g[8];
    float m = -3.4e38f;
#pragma unroll
    for (int j = 0; j < 8; j++) { g[j] = gp[(size_t)j << 16]; m = fmaxf(m, g[j]); }
    float s = 0.f;
#pragma unroll
    for (int j = 0; j < 8; j++) { g[j] = expf(g[j] - m); s += g[j]; }
    float inv = 1.0f / s;
    float d = depth[(((size_t)b) << 16) + hw];
    bool fixed = d > 0.f;   // sign(depth) is 0/1 (depth >= 0)
    float* wp = wts + (size_t)idx * 9;
#pragma unroll
    for (int j = 0; j < 9; j++) {
        float v;
        if (j == 4) v = fixed ? 1.f : 0.f;            // center
        else        v = fixed ? 0.f : g[j - (j > 4 ? 1 : 0)] * inv;
        wp[j] = v;
    }
}

// acc[k] += wf[9k + (3i+j)] * rb[i][k+j]  — same fmaf order as R3/R4 (passed).
__device__ __forceinline__ void stencil4(const float wf[36],
                                         const float rb[3][6],
                                         float acc[4]) {
#pragma unroll
    for (int i = 0; i < 3; ++i)
#pragma unroll
        for (int j = 0; j < 3; ++j)
#pragma unroll
            for (int k = 0; k < 4; ++k)
                acc[k] = fmaf(wf[9 * k + i * 3 + j], rb[i][k + j], acc[k]);
}

// Two fused propagation steps. Block (64,4): one wave == one full 256-wide
// row (64 lanes x 4 px). Halos via wave shfl (no scalar loads, 0 conflicts).
__global__ __launch_bounds__(256)
void prop2_kernel(const float* __restrict__ xin,
                  const float* __restrict__ wts,
                  float* __restrict__ xout) {
    __shared__ float mid[CPB][MIDR][W_];   // 20.5 KB
    const int tx = threadIdx.x;            // 0..63
    const int ty = threadIdx.y;            // 0..3
    const int h0 = blockIdx.x * STRIP;
    const int c0 = blockIdx.y * CPB;
    const int b  = blockIdx.z;
    const int w0 = tx * 4;
    const size_t plane = (size_t)H_ * W_;
    const bool hasL = (tx > 0), hasR = (tx < 63);

    // ---- Phase 1: step-1 on rows h0-1 .. h0+STRIP, into LDS ----
    for (int rr = ty; rr < MIDR; rr += 4) {
        const int r = h0 - 1 + rr;
        if (r < 0 || r >= H_) {
            float4 z = {0.f, 0.f, 0.f, 0.f};
#pragma unroll
            for (int c = 0; c < CPB; ++c)
                *reinterpret_cast<float4*>(&mid[c][rr][w0]) = z;
            continue;
        }
        // pixel-major weights: contiguous 144B per thread
        const float* wp = wts + ((size_t)(b * H_ + r) * W_ + w0) * 9;
        float wf[36];
#pragma unroll
        for (int j = 0; j < 9; ++j)
            *reinterpret_cast<float4*>(&wf[4 * j]) =
                *reinterpret_cast<const float4*>(wp + 4 * j);
#pragma unroll
        for (int c = 0; c < CPB; ++c) {
            const float* xc = xin + ((size_t)b * C_ + (c0 + c)) * plane;
            float rb[3][6];
#pragma unroll
            for (int i = 0; i < 3; ++i) {
                int row = r - 1 + i;
                if (row >= 0 && row < H_) {
                    float4 v = *reinterpret_cast<const float4*>(
                        xc + (size_t)row * W_ + w0);
                    float lh = __shfl_up(v.w, 1);
                    float rhv = __shfl_down(v.x, 1);
                    rb[i][0] = hasL ? lh : 0.f;
                    rb[i][1] = v.x; rb[i][2] = v.y; rb[i][3] = v.z; rb[i][4] = v.w;
                    rb[i][5] = hasR ? rhv : 0.f;
                } else {
#pragma unroll
                    for (int t = 0; t < 6; ++t) rb[i][t] = 0.f;
                }
            }
            float acc[4] = {0.f, 0.f, 0.f, 0.f};
            stencil4(wf, rb, acc);
            float4 o = {acc[0], acc[1], acc[2], acc[3]};
            *reinterpret_cast<float4*>(&mid[c][rr][w0]) = o;
        }
    }
    __syncthreads();

    // ---- Phase 2: step-2 on rows h0 .. h0+STRIP-1, LDS -> global ----
    for (int rr = ty; rr < STRIP; rr += 4) {
        const int r = h0 + rr;
        const float* wp = wts + ((size_t)(b * H_ + r) * W_ + w0) * 9;
        float wf[36];
#pragma unroll
        for (int j = 0; j < 9; ++j)
            *reinterpret_cast<float4*>(&wf[4 * j]) =
                *reinterpret_cast<const float4*>(wp + 4 * j);
#pragma unroll
        for (int c = 0; c < CPB; ++c) {
            float rb[3][6];
#pragma unroll
            for (int i = 0; i < 3; ++i) {
                // mid index rr+i corresponds to global row r-1+i
                float4 v = *reinterpret_cast<const float4*>(&mid[c][rr + i][w0]);
                float lh = __shfl_up(v.w, 1);
                float rhv = __shfl_down(v.x, 1);
                rb[i][0] = hasL ? lh : 0.f;
                rb[i][1] = v.x; rb[i][2] = v.y; rb[i][3] = v.z; rb[i][4] = v.w;
                rb[i][5] = hasR ? rhv : 0.f;
            }
            float acc[4] = {0.f, 0.f, 0.f, 0.f};
            stencil4(wf, rb, acc);
            float4 o = {acc[0], acc[1], acc[2], acc[3]};
            *reinterpret_cast<float4*>(xout + ((size_t)b * C_ + (c0 + c)) * plane +
                                       (size_t)r * W_ + w0) = o;
        }
    }
}

extern "C" void kernel_launch(void* const* d_in, const int* in_sizes, int n_in,
                              void* d_out, int out_size, void* d_ws, size_t ws_size,
                              hipStream_t stream) {
    const float* x      = (const float*)d_in[0];
    const float* guided = (const float*)d_in[1];
    const float* depth  = (const float*)d_in[2];
    // d_in[3] = prop_time; fixed to 16 by setup_inputs.
    const int FUSED_STEPS = 8;   // 16 propagation steps, 2 per kernel

    float* xbuf = (float*)d_ws;                                   // 64 MB
    float* wts  = (float*)((char*)d_ws +
                           (size_t)B_ * C_ * H_ * W_ * sizeof(float)); // 18.9 MB
    float* out  = (float*)d_out;

    int total = B_ * H_ * W_;
    hipLaunchKernelGGL(prep_weights_kernel, dim3((total + 255) / 256), dim3(256),
                       0, stream, guided, depth, wts, total);

    dim3 grid(H_ / STRIP, C_ / CPB, B_), block(64, 4, 1);
    const float* src = x;
    for (int t = 0; t < FUSED_STEPS; ++t) {
        float* dst = (t == FUSED_STEPS - 1) ? out : ((t % 2 == 0) ? xbuf : out);
        hipLaunchKernelGGL(prop2_kernel, grid, block, 0, stream,
                           src, wts, dst);
        src = dst;
    }
}

// Round 10
// 352.808 us; speedup vs baseline: 3.7640x; 1.4961x over previous
//
#include <hip/hip_runtime.h>

// AffinityPropagate (CSPN): B=8, C=32, H=W=256, K=3, prop_time=16.
// R9: single-variable test — R4 structure (CPB=2, STRIP=16, shfl halos,
// no min-waves bound) but weights back to PLANAR (b,9,H,W) layout so each
// of the 9 weight loads is fully coalesced (16 cache lines/load, not 64).
// Theory: pixel-major weight loads were L1-tag/line-amplified 4x and were
// the real limiter pinning every config at ~86-98us.

#define B_ 8
#define C_ 32
#define H_ 256
#define W_ 256
#define STRIP 16
#define CPB 2
#define MIDR (STRIP + 2)

// Planar weights: wts[((b*9)+j)*H*W + h*W + w]
__global__ __launch_bounds__(256)
void prep_weights_kernel(const float* __restrict__ guided,
                         const float* __restrict__ depth,
                         float* __restrict__ wts,
                         int total /* B*H*W */) {
    int idx = blockIdx.x * 256 + threadIdx.x;
    if (idx >= total) return;
    int b  = idx >> 16;        // H*W = 65536
    int hw = idx & 0xFFFF;
    const float* gp = guided + (((size_t)b * 8) << 16) + hw;
    float g[8];
    float m = -3.4e38f;
#pragma unroll
    for (int j = 0; j < 8; j++) { g[j] = gp[(size_t)j << 16]; m = fmaxf(m, g[j]); }
    float s = 0.f;
#pragma unroll
    for (int j = 0; j < 8; j++) { g[j] = expf(g[j] - m); s += g[j]; }
    float inv = 1.0f / s;
    float d = depth[(((size_t)b) << 16) + hw];
    bool fixed = d > 0.f;   // sign(depth) is 0/1 (depth >= 0)
    float* wp = wts + (((size_t)b * 9) << 16) + hw;
#pragma unroll
    for (int j = 0; j < 9; j++) {
        float v;
        if (j == 4) v = fixed ? 1.f : 0.f;            // center
        else        v = fixed ? 0.f : g[j - (j > 4 ? 1 : 0)] * inv;
        wp[(size_t)j << 16] = v;
    }
}

// acc[k] += wgt[3i+j][k] * rb[i][k+j]  — same fmaf order as R3/R4 (passed).
__device__ __forceinline__ void stencil4(const float wgt[9][4],
                                         const float rb[3][6],
                                         float acc[4]) {
#pragma unroll
    for (int i = 0; i < 3; ++i)
#pragma unroll
        for (int j = 0; j < 3; ++j)
#pragma unroll
            for (int k = 0; k < 4; ++k)
                acc[k] = fmaf(wgt[i * 3 + j][k], rb[i][k + j], acc[k]);
}

// Two fused propagation steps. Block (64,4): one wave == one full 256-wide
// row (64 lanes x 4 px). Halos via wave shfl (no scalar loads, 0 conflicts).
__global__ __launch_bounds__(256)
void prop2_kernel(const float* __restrict__ xin,
                  const float* __restrict__ wts,
                  float* __restrict__ xout) {
    __shared__ float mid[CPB][MIDR][W_];   // 36 KB
    const int tx = threadIdx.x;            // 0..63
    const int ty = threadIdx.y;            // 0..3
    const int h0 = blockIdx.x * STRIP;
    const int c0 = blockIdx.y * CPB;
    const int b  = blockIdx.z;
    const int w0 = tx * 4;
    const size_t plane = (size_t)H_ * W_;
    const bool hasL = (tx > 0), hasR = (tx < 63);

    // ---- Phase 1: step-1 on rows h0-1 .. h0+STRIP, into LDS ----
    for (int rr = ty; rr < MIDR; rr += 4) {
        const int r = h0 - 1 + rr;
        if (r < 0 || r >= H_) {
            float4 z = {0.f, 0.f, 0.f, 0.f};
#pragma unroll
            for (int c = 0; c < CPB; ++c)
                *reinterpret_cast<float4*>(&mid[c][rr][w0]) = z;
            continue;
        }
        // planar weights: 9 fully-coalesced float4 loads (1KB/wave each)
        const float* wp = wts + (size_t)b * 9 * plane + (size_t)r * W_ + w0;
        float wgt[9][4];
#pragma unroll
        for (int j = 0; j < 9; ++j) {
            float4 v = *reinterpret_cast<const float4*>(wp + j * plane);
            wgt[j][0] = v.x; wgt[j][1] = v.y; wgt[j][2] = v.z; wgt[j][3] = v.w;
        }
#pragma unroll
        for (int c = 0; c < CPB; ++c) {
            const float* xc = xin + ((size_t)b * C_ + (c0 + c)) * plane;
            float rb[3][6];
#pragma unroll
            for (int i = 0; i < 3; ++i) {
                int row = r - 1 + i;
                if (row >= 0 && row < H_) {
                    float4 v = *reinterpret_cast<const float4*>(
                        xc + (size_t)row * W_ + w0);
                    float lh = __shfl_up(v.w, 1);
                    float rhv = __shfl_down(v.x, 1);
                    rb[i][0] = hasL ? lh : 0.f;
                    rb[i][1] = v.x; rb[i][2] = v.y; rb[i][3] = v.z; rb[i][4] = v.w;
                    rb[i][5] = hasR ? rhv : 0.f;
                } else {
#pragma unroll
                    for (int t = 0; t < 6; ++t) rb[i][t] = 0.f;
                }
            }
            float acc[4] = {0.f, 0.f, 0.f, 0.f};
            stencil4(wgt, rb, acc);
            float4 o = {acc[0], acc[1], acc[2], acc[3]};
            *reinterpret_cast<float4*>(&mid[c][rr][w0]) = o;
        }
    }
    __syncthreads();

    // ---- Phase 2: step-2 on rows h0 .. h0+STRIP-1, LDS -> global ----
    for (int rr = ty; rr < STRIP; rr += 4) {
        const int r = h0 + rr;
        const float* wp = wts + (size_t)b * 9 * plane + (size_t)r * W_ + w0;
        float wgt[9][4];
#pragma unroll
        for (int j = 0; j < 9; ++j) {
            float4 v = *reinterpret_cast<const float4*>(wp + j * plane);
            wgt[j][0] = v.x; wgt[j][1] = v.y; wgt[j][2] = v.z; wgt[j][3] = v.w;
        }
#pragma unroll
        for (int c = 0; c < CPB; ++c) {
            float rb[3][6];
#pragma unroll
            for (int i = 0; i < 3; ++i) {
                // mid index rr+i corresponds to global row r-1+i
                float4 v = *reinterpret_cast<const float4*>(&mid[c][rr + i][w0]);
                float lh = __shfl_up(v.w, 1);
                float rhv = __shfl_down(v.x, 1);
                rb[i][0] = hasL ? lh : 0.f;
                rb[i][1] = v.x; rb[i][2] = v.y; rb[i][3] = v.z; rb[i][4] = v.w;
                rb[i][5] = hasR ? rhv : 0.f;
            }
            float acc[4] = {0.f, 0.f, 0.f, 0.f};
            stencil4(wgt, rb, acc);
            float4 o = {acc[0], acc[1], acc[2], acc[3]};
            *reinterpret_cast<float4*>(xout + ((size_t)b * C_ + (c0 + c)) * plane +
                                       (size_t)r * W_ + w0) = o;
        }
    }
}

extern "C" void kernel_launch(void* const* d_in, const int* in_sizes, int n_in,
                              void* d_out, int out_size, void* d_ws, size_t ws_size,
                              hipStream_t stream) {
    const float* x      = (const float*)d_in[0];
    const float* guided = (const float*)d_in[1];
    const float* depth  = (const float*)d_in[2];
    // d_in[3] = prop_time; fixed to 16 by setup_inputs.
    const int FUSED_STEPS = 8;   // 16 propagation steps, 2 per kernel

    float* xbuf = (float*)d_ws;                                   // 64 MB
    float* wts  = (float*)((char*)d_ws +
                           (size_t)B_ * C_ * H_ * W_ * sizeof(float)); // 18.9 MB
    float* out  = (float*)d_out;

    int total = B_ * H_ * W_;
    hipLaunchKernelGGL(prep_weights_kernel, dim3((total + 255) / 256), dim3(256),
                       0, stream, guided, depth, wts, total);

    dim3 grid(H_ / STRIP, C_ / CPB, B_), block(64, 4, 1);
    const float* src = x;
    for (int t = 0; t < FUSED_STEPS; ++t) {
        float* dst = (t == FUSED_STEPS - 1) ? out : ((t % 2 == 0) ? xbuf : out);
        hipLaunchKernelGGL(prop2_kernel, grid, block, 0, stream,
                           src, wts, dst);
        src = dst;
    }
}